// Round 3
// baseline (1293.242 us; speedup 1.0000x reference)
//
#include <hip/hip_runtime.h>
#include <hip/hip_bf16.h>
#include <cstdint>
#include <math.h>

#define S_TOT 16384
#define V_VOC 2048
#define B_B   32
#define T_T   64
#define L_L   16

// workspace layout (bytes)
static const size_t OFF_ET  = 0;                   // Et bf16 [V][S]: 67108864
static const size_t OFF_EM  = 67108864;            // em f32 [B*T][S]: 134217728
static const size_t OFF_LSE = OFF_EM + 134217728;  // row_lse f32 [S]
static const size_t OFF_TT  = OFF_LSE + 65536;     // Tt bf16 [7][S]

__device__ __forceinline__ unsigned short f2bf(float f) {
  unsigned int u = __float_as_uint(f);
  u = (u + 0x7fffu + ((u >> 16) & 1u)) >> 16;   // round-to-nearest-even
  return (unsigned short)u;
}
__device__ __forceinline__ float bflo(unsigned int w) { return __uint_as_float(w << 16); }
__device__ __forceinline__ float bfhi(unsigned int w) { return __uint_as_float(w & 0xffff0000u); }

// ---- DPP helpers (VALU cross-lane, keeps LDS pipe free). ctrl must be ICE -> template param.
template <int CTRL>
__device__ __forceinline__ float dppf(float v) {
  return __int_as_float(__builtin_amdgcn_update_dpp(0, __float_as_int(v), CTRL, 0xf, 0xf, true));
}
__device__ __forceinline__ float dpp_rshr1(float v) { return dppf<0x111>(v); } // lane gets lane-1 (row of 16)
__device__ __forceinline__ float dpp_rshl1(float v) { return dppf<0x101>(v); } // lane gets lane+1
__device__ __forceinline__ float wave_sum64(float v) {
  v += dppf<0xB1>(v);   // quad_perm {1,0,3,2}
  v += dppf<0x4E>(v);   // quad_perm {2,3,0,1}
  v += dppf<0x141>(v);  // row_half_mirror
  v += dppf<0x140>(v);  // row_mirror
  v += __shfl_xor(v, 16);
  v += __shfl_xor(v, 32);
  return v;
}
__device__ __forceinline__ float wave_max64(float v) {
  v = fmaxf(v, dppf<0xB1>(v));
  v = fmaxf(v, dppf<0x4E>(v));
  v = fmaxf(v, dppf<0x141>(v));
  v = fmaxf(v, dppf<0x140>(v));
  v = fmaxf(v, __shfl_xor(v, 16));
  v = fmaxf(v, __shfl_xor(v, 32));
  return v;
}

// ---------------- K1: per-state logsumexp over vocab ----------------
__global__ void k_row_lse(const float* __restrict__ W, float* __restrict__ lse) {
  const int row = blockIdx.x;
  const int tid = threadIdx.x;          // 128 threads, 2 waves
  const float4* rp = (const float4*)(W + (size_t)row * V_VOC);
  float v[16];
#pragma unroll
  for (int j = 0; j < 4; ++j) {
    float4 q = rp[tid + j * 128];
    v[4*j+0] = q.x; v[4*j+1] = q.y; v[4*j+2] = q.z; v[4*j+3] = q.w;
  }
  float m = v[0];
#pragma unroll
  for (int j = 1; j < 16; ++j) m = fmaxf(m, v[j]);
  m = wave_max64(m);
  __shared__ float sm[2];
  __shared__ float ss[2];
  const int wid = tid >> 6;
  if ((tid & 63) == 0) sm[wid] = m;
  __syncthreads();
  m = fmaxf(sm[0], sm[1]);
  float s = 0.f;
#pragma unroll
  for (int j = 0; j < 16; ++j) s += expf(v[j] - m);
  s = wave_sum64(s);
  if ((tid & 63) == 0) ss[wid] = s;
  __syncthreads();
  if (tid == 0) lse[row] = m + logf(ss[0] + ss[1]);
}

// ---------------- K2: transpose W (S,V) f32 -> Et (V,S) bf16 ----------------
__global__ void k_transpose(const float* __restrict__ W, unsigned short* __restrict__ Et) {
  __shared__ float t[64][33];           // [s][v], padded
  const int s0 = blockIdx.x * 64;
  const int v0 = blockIdx.y * 32;
  const int tid = threadIdx.x;          // 256
  const int r = tid >> 3, c = (tid & 7) * 4;
#pragma unroll
  for (int it = 0; it < 2; ++it) {
    const float* src = W + (size_t)(s0 + r + it * 32) * V_VOC + v0 + c;
    float4 q = *(const float4*)src;
    t[r + it * 32][c + 0] = q.x; t[r + it * 32][c + 1] = q.y;
    t[r + it * 32][c + 2] = q.z; t[r + it * 32][c + 3] = q.w;
  }
  __syncthreads();
  const int vv = tid >> 3, cs = (tid & 7) * 8;
  unsigned int w0 = (unsigned int)f2bf(t[cs + 0][vv]) | ((unsigned int)f2bf(t[cs + 1][vv]) << 16);
  unsigned int w1 = (unsigned int)f2bf(t[cs + 2][vv]) | ((unsigned int)f2bf(t[cs + 3][vv]) << 16);
  unsigned int w2 = (unsigned int)f2bf(t[cs + 4][vv]) | ((unsigned int)f2bf(t[cs + 5][vv]) << 16);
  unsigned int w3 = (unsigned int)f2bf(t[cs + 6][vv]) | ((unsigned int)f2bf(t[cs + 7][vv]) << 16);
  uint4 out = make_uint4(w0, w1, w2, w3);
  *(uint4*)(Et + (size_t)(v0 + vv) * S_TOT + s0 + cs) = out;
}

// ---------------- K3: transition softmax -> probabilities, (7,S) bf16 ----------------
__global__ void k_tsoftmax(const float* __restrict__ tw, unsigned short* __restrict__ Tt) {
  const int s = blockIdx.x * 256 + threadIdx.x;
  float x[7];
#pragma unroll
  for (int k = 0; k < 7; ++k) x[k] = tw[(size_t)s * 7 + k];
  float m = x[0];
#pragma unroll
  for (int k = 1; k < 7; ++k) m = fmaxf(m, x[k]);
  float e[7]; float sum = 0.f;
#pragma unroll
  for (int k = 0; k < 7; ++k) { e[k] = expf(x[k] - m); sum += e[k]; }
  const float inv = 1.f / sum;
#pragma unroll
  for (int k = 0; k < 7; ++k) Tt[(size_t)k * S_TOT + s] = f2bf(e[k] * inv);
}

// ---------------- K4: em[bt,s] = sum_l Et[tok_l][s] - L*lse[s] ----------------
__global__ void k_em(const unsigned short* __restrict__ Et, const int* __restrict__ stories,
                     const float* __restrict__ lse, float* __restrict__ em) {
  const int bt = blockIdx.y;
  __shared__ int toks[L_L];
  if (threadIdx.x < L_L) toks[threadIdx.x] = stories[bt * L_L + threadIdx.x];
  __syncthreads();
  const int s = blockIdx.x * 2048 + threadIdx.x * 8;
  float acc[8] = {0.f, 0.f, 0.f, 0.f, 0.f, 0.f, 0.f, 0.f};
#pragma unroll
  for (int l = 0; l < L_L; ++l) {
    const uint4* p = (const uint4*)(Et + ((size_t)toks[l] << 14) + s);
    uint4 q = *p;
    acc[0] += bflo(q.x); acc[1] += bfhi(q.x);
    acc[2] += bflo(q.y); acc[3] += bfhi(q.y);
    acc[4] += bflo(q.z); acc[5] += bfhi(q.z);
    acc[6] += bflo(q.w); acc[7] += bfhi(q.w);
  }
  const float4* lp = (const float4*)(lse + s);
  float4 l0 = lp[0], l1 = lp[1];
  float4 o0, o1;
  o0.x = acc[0] - 16.f * l0.x; o0.y = acc[1] - 16.f * l0.y;
  o0.z = acc[2] - 16.f * l0.z; o0.w = acc[3] - 16.f * l0.w;
  o1.x = acc[4] - 16.f * l1.x; o1.y = acc[5] - 16.f * l1.y;
  o1.z = acc[6] - 16.f * l1.z; o1.w = acc[7] - 16.f * l1.w;
  float4* op = (float4*)(em + (size_t)bt * S_TOT + s);
  op[0] = o0; op[1] = o1;
}

// ---------------- K5: scaled forward recursion, one block per batch ----------------
// Layout: thread owns 2 consecutive x (pair) x 8 z.  x+-1 via DPP, z via regs, y via LDS float2.
// One barrier per step: Z-partials (this step) and em-max (next step) publish together.

__device__ __forceinline__ float block_sum16(float v, float* row, int tid, int wid) {
  v = wave_sum64(v);
  if ((tid & 63) == 0) row[wid] = v;
  __syncthreads();
  const float4* p4 = (const float4*)row;
  float4 a = p4[0], b = p4[1], c = p4[2], d = p4[3];
  return ((a.x + a.y) + (a.z + a.w)) + ((b.x + b.y) + (b.z + b.w))
       + ((c.x + c.y) + (c.z + c.w)) + ((d.x + d.y) + (d.z + d.w));
}
__device__ __forceinline__ float block_max16(float v, float* row, int tid, int wid) {
  v = wave_max64(v);
  if ((tid & 63) == 0) row[wid] = v;
  __syncthreads();
  const float4* p4 = (const float4*)row;
  float4 a = p4[0], b = p4[1], c = p4[2], d = p4[3];
  return fmaxf(fmaxf(fmaxf(fmaxf(a.x,a.y),fmaxf(a.z,a.w)), fmaxf(fmaxf(b.x,b.y),fmaxf(b.z,b.w))),
               fmaxf(fmaxf(fmaxf(c.x,c.y),fmaxf(c.z,c.w)), fmaxf(fmaxf(d.x,d.y),fmaxf(d.z,d.w))));
}

#define TLO(k,i) __uint_as_float(Tp[k][i] << 16)
#define THI(k,i) __uint_as_float(Tp[k][i] & 0xffff0000u)

__launch_bounds__(1024, 4)
__global__ void k_forward(const float* __restrict__ em, const float* __restrict__ prior_w,
                          const unsigned short* __restrict__ Tt, float* __restrict__ out) {
  __shared__ __align__(16) float qbuf[2][16448];   // interior at [32, 16416)
  __shared__ __align__(16) float partS[2][16];
  __shared__ __align__(16) float partM[2][16];
  __shared__ __align__(16) float scr0[5][16];
  const int tid = threadIdx.x;
  const int b   = blockIdx.x;
  const int ux = tid & 15, uy = (tid >> 4) & 31, uz = tid >> 9;
  const int rowxy = uy * 32 + 2 * ux;
  const int soff  = uz * 8192 + rowxy;             // state index of (i=0, j=0)
  const int zoff  = uz ? (6144 + rowxy) : rowxy;   // z-2 plane base (clamped, garbage masked)
  const int wid = tid >> 6;

  if (tid < 64) {                                  // zero guards (read via y-offsets, masked by T=0)
    int g = (tid < 32) ? tid : (16416 + tid - 32);
    qbuf[0][g] = 0.f; qbuf[1][g] = 0.f;
  }

  const float* emb = em + (size_t)b * T_T * S_TOT;

  // ---- t = 0 (+ prefetch em[t=1] into emA) ----
  float2 emA[8], emB[8];
#pragma unroll
  for (int i = 0; i < 8; ++i) emA[i] = *(const float2*)(emb + S_TOT + soff + i * 1024);

  float2 pw[8], e0[8];
#pragma unroll
  for (int i = 0; i < 8; ++i) pw[i] = *(const float2*)(prior_w + soff + i * 1024);
#pragma unroll
  for (int i = 0; i < 8; ++i) e0[i] = *(const float2*)(emb + soff + i * 1024);

  float pm = fmaxf(pw[0].x, pw[0].y);
#pragma unroll
  for (int i = 1; i < 8; ++i) pm = fmaxf(pm, fmaxf(pw[i].x, pw[i].y));
  const float Mp = block_max16(pm, scr0[0], tid, wid);
  float pse = 0.f;
#pragma unroll
  for (int i = 0; i < 8; ++i) pse += __expf(pw[i].x - Mp) + __expf(pw[i].y - Mp);
  const float Sp = block_sum16(pse, scr0[1], tid, wid);
  const float prior_lse = Mp + __logf(Sp);

  float vm = e0[0].x + pw[0].x;
#pragma unroll
  for (int i = 0; i < 8; ++i) vm = fmaxf(vm, fmaxf(e0[i].x + pw[i].x, e0[i].y + pw[i].y));
  const float M0 = block_max16(vm, scr0[2], tid, wid);

  float2 qrv[8]; float ps0 = 0.f;
#pragma unroll
  for (int i = 0; i < 8; ++i) {
    float u0 = __expf(e0[i].x + pw[i].x - M0);
    float u1 = __expf(e0[i].y + pw[i].y - M0);
    qrv[i] = make_float2(u0, u1);
    *(float2*)(&qbuf[0][32 + soff + i * 1024]) = qrv[i];
    ps0 += u0 + u1;
  }
  const float Z0 = block_sum16(ps0, scr0[3], tid, wid);
  const float lgZ = __logf(Z0);
  float C = M0 - prior_lse + lgZ;

  // M for t=1 from prefetched emA
  float a1 = fmaxf(emA[0].x, emA[0].y);
#pragma unroll
  for (int i = 1; i < 8; ++i) a1 = fmaxf(a1, fmaxf(emA[i].x, emA[i].y));
  const float M1reg = block_max16(a1, scr0[4], tid, wid);

  // ---- transition table into registers (after t0 so pw/e0 regs are dead) ----
  unsigned Tp[7][8];
  const int offs[7] = {0, 1, -1, 32, -32, 1024, 2048};
#pragma unroll
  for (int k = 0; k < 7; ++k) {
#pragma unroll
    for (int i = 0; i < 8; ++i) {
      unsigned w = 0;
#pragma unroll
      for (int j = 0; j < 2; ++j) {
        const int x = 2 * ux + j, z = uz * 8 + i;
        const int si = soff + i * 1024 + j;
        int prev = si - offs[k];
        prev = prev < 0 ? 0 : (prev > S_TOT - 1 ? S_TOT - 1 : prev);
        const bool valid = (k == 0)
          || (k == 1 && x > 0)  || (k == 2 && x < 31)
          || (k == 3 && uy > 0) || (k == 4 && uy < 31)
          || (k == 5 && z >= 1) || (k == 6 && z >= 2);
        unsigned tv = valid ? (unsigned)Tt[(size_t)k * S_TOT + prev] : 0u;
        w |= tv << (16 * j);
      }
      Tp[k][i] = w;
    }
  }

#define STEP(TT, EMC, EMN, FIRST) { \
    const int tt = (TT); \
    { const int tn = (tt + 1 < T_T) ? (tt + 1) : (T_T - 1); \
      const float* en = emb + (size_t)tn * S_TOT + soff; \
      _Pragma("unroll") for (int i = 0; i < 8; ++i) EMN[i] = *(const float2*)(en + i * 1024); } \
    float Mt, lzp; \
    if (FIRST) { Mt = M1reg; lzp = lgZ; } \
    else { \
      const float4* pS = (const float4*)partS[(tt - 1) & 1]; \
      float4 sa = pS[0], sb = pS[1], sc = pS[2], sd = pS[3]; \
      float Zp = ((sa.x+sa.y)+(sa.z+sa.w))+((sb.x+sb.y)+(sb.z+sb.w)) \
               + ((sc.x+sc.y)+(sc.z+sc.w))+((sd.x+sd.y)+(sd.z+sd.w)); \
      lzp = __logf(Zp); C += lzp; \
      const float4* pM = (const float4*)partM[tt & 1]; \
      float4 ma = pM[0], mb = pM[1], mc = pM[2], md = pM[3]; \
      Mt = fmaxf(fmaxf(fmaxf(fmaxf(ma.x,ma.y),fmaxf(ma.z,ma.w)), fmaxf(fmaxf(mb.x,mb.y),fmaxf(mb.z,mb.w))), \
                 fmaxf(fmaxf(fmaxf(mc.x,mc.y),fmaxf(mc.z,mc.w)), fmaxf(fmaxf(md.x,md.y),fmaxf(md.z,md.w)))); \
    } \
    C += Mt; \
    const float shift = Mt + lzp; \
    const float* qc = &qbuf[(tt - 1) & 1][32]; \
    float* qw = &qbuf[tt & 1][32]; \
    float2 q2v = *(const float2*)(qc + zoff); \
    float2 q1v = *(const float2*)(qc + zoff + 1024); \
    float ps = 0.f; \
    _Pragma("unroll") for (int i = 0; i < 8; ++i) { \
      const int si = soff + i * 1024; \
      float2 ym = *(const float2*)(qc + si - 32); \
      float2 yp = *(const float2*)(qc + si + 32); \
      const float2 qo = qrv[i]; \
      const float xl = dpp_rshr1(qo.y); \
      const float xr = dpp_rshl1(qo.x); \
      float sig0 = qo.x*TLO(0,i) + xl*TLO(1,i) + qo.y*TLO(2,i) + ym.x*TLO(3,i) \
                 + yp.x*TLO(4,i) + q1v.x*TLO(5,i) + q2v.x*TLO(6,i); \
      float sig1 = qo.y*THI(0,i) + qo.x*THI(1,i) + xr*THI(2,i) + ym.y*THI(3,i) \
                 + yp.y*THI(4,i) + q1v.y*THI(5,i) + q2v.y*THI(6,i); \
      const float u0 = __expf(EMC[i].x - shift) * sig0; \
      const float u1 = __expf(EMC[i].y - shift) * sig1; \
      ps += u0 + u1; \
      const float2 uu = make_float2(u0, u1); \
      qrv[i] = uu; \
      *(float2*)(qw + si) = uu; \
      q2v = q1v; q1v = qo; \
    } \
    float nm = fmaxf(EMN[0].x, EMN[0].y); \
    _Pragma("unroll") for (int i = 1; i < 8; ++i) nm = fmaxf(nm, fmaxf(EMN[i].x, EMN[i].y)); \
    nm = wave_max64(nm); \
    ps = wave_sum64(ps); \
    if ((tid & 63) == 0) { partS[tt & 1][wid] = ps; partM[(tt + 1) & 1][wid] = nm; } \
    __syncthreads(); \
  }

  STEP(1, emA, emB, 1)
  for (int t = 2; t < T_T; t += 2) {
    STEP(t,     emB, emA, 0)
    STEP(t + 1, emA, emB, 0)
  }
  { // epilogue: Z for t=63 sits in partS[63&1 = 1]
    const float4* pS = (const float4*)partS[1];
    float4 sa = pS[0], sb = pS[1], sc = pS[2], sd = pS[3];
    float Zf = ((sa.x+sa.y)+(sa.z+sa.w))+((sb.x+sb.y)+(sb.z+sb.w))
             + ((sc.x+sc.y)+(sc.z+sc.w))+((sd.x+sd.y)+(sd.z+sd.w));
    C += __logf(Zf);
  }
  if (tid == 0) out[b] = C;
#undef STEP
}

extern "C" void kernel_launch(void* const* d_in, const int* in_sizes, int n_in,
                              void* d_out, int out_size, void* d_ws, size_t ws_size,
                              hipStream_t stream) {
  (void)in_sizes; (void)n_in; (void)out_size; (void)ws_size;
  const int*   stories      = (const int*)d_in[0];
  const float* emission_w   = (const float*)d_in[3];
  const float* transition_w = (const float*)d_in[4];
  const float* prior_w      = (const float*)d_in[5];
  float* out = (float*)d_out;
  char* ws = (char*)d_ws;
  unsigned short* Et = (unsigned short*)(ws + OFF_ET);
  float*          em = (float*)(ws + OFF_EM);
  float*         lse = (float*)(ws + OFF_LSE);
  unsigned short* Tt = (unsigned short*)(ws + OFF_TT);

  hipLaunchKernelGGL(k_row_lse,   dim3(S_TOT),   dim3(128), 0, stream, emission_w, lse);
  hipLaunchKernelGGL(k_transpose, dim3(256, 64), dim3(256), 0, stream, emission_w, Et);
  hipLaunchKernelGGL(k_tsoftmax,  dim3(64),      dim3(256), 0, stream, transition_w, Tt);
  hipLaunchKernelGGL(k_em,        dim3(8, 2048), dim3(256), 0, stream, Et, stories, lse, em);
  hipLaunchKernelGGL(k_forward,   dim3(B_B),     dim3(1024), 0, stream, em, prior_w, Tt, out);
}

// Round 6
// 1214.522 us; speedup vs baseline: 1.0648x; 1.0648x over previous
//
#include <hip/hip_runtime.h>
#include <hip/hip_bf16.h>
#include <cstdint>
#include <math.h>

#define S_TOT 16384
#define V_VOC 2048
#define B_B   32
#define T_T   64
#define L_L   16

// workspace layout (bytes)
static const size_t OFF_ET  = 0;                   // Et bf16 [V][S]: 67108864
static const size_t OFF_EM  = 67108864;            // em f32 [B*T][S]: 134217728
static const size_t OFF_LSE = OFF_EM + 134217728;  // row_lse f32 [S]
static const size_t OFF_TT  = OFF_LSE + 65536;     // Tt bf16 [7][S]

__device__ __forceinline__ unsigned short f2bf(float f) {
  unsigned int u = __float_as_uint(f);
  u = (u + 0x7fffu + ((u >> 16) & 1u)) >> 16;   // round-to-nearest-even
  return (unsigned short)u;
}
__device__ __forceinline__ float bflo(unsigned int w) { return __uint_as_float(w << 16); }
__device__ __forceinline__ float bfhi(unsigned int w) { return __uint_as_float(w & 0xffff0000u); }

// ---- DPP helpers (VALU cross-lane, keeps LDS pipe free). ctrl must be ICE -> template param.
template <int CTRL>
__device__ __forceinline__ float dppf(float v) {
  return __int_as_float(__builtin_amdgcn_update_dpp(0, __float_as_int(v), CTRL, 0xf, 0xf, true));
}
__device__ __forceinline__ float dpp_rshr1(float v) { return dppf<0x111>(v); } // lane gets lane-1 (row of 16)
__device__ __forceinline__ float dpp_rshl1(float v) { return dppf<0x101>(v); } // lane gets lane+1
__device__ __forceinline__ float row16_sum(float v) {
  v += dppf<0xB1>(v);   // quad_perm {1,0,3,2}
  v += dppf<0x4E>(v);   // quad_perm {2,3,0,1}
  v += dppf<0x141>(v);  // row_half_mirror
  v += dppf<0x140>(v);  // row_mirror
  return v;
}
__device__ __forceinline__ float row16_max(float v) {
  v = fmaxf(v, dppf<0xB1>(v));
  v = fmaxf(v, dppf<0x4E>(v));
  v = fmaxf(v, dppf<0x141>(v));
  v = fmaxf(v, dppf<0x140>(v));
  return v;
}
__device__ __forceinline__ float wave_sum64(float v) {
  v = row16_sum(v);
  v += __shfl_xor(v, 16);
  v += __shfl_xor(v, 32);
  return v;
}
__device__ __forceinline__ float wave_max64(float v) {
  v = row16_max(v);
  v = fmaxf(v, __shfl_xor(v, 16));
  v = fmaxf(v, __shfl_xor(v, 32));
  return v;
}

// ---------------- K1: per-state logsumexp over vocab ----------------
__global__ void k_row_lse(const float* __restrict__ W, float* __restrict__ lse) {
  const int row = blockIdx.x;
  const int tid = threadIdx.x;          // 128 threads, 2 waves
  const float4* rp = (const float4*)(W + (size_t)row * V_VOC);
  float v[16];
#pragma unroll
  for (int j = 0; j < 4; ++j) {
    float4 q = rp[tid + j * 128];
    v[4*j+0] = q.x; v[4*j+1] = q.y; v[4*j+2] = q.z; v[4*j+3] = q.w;
  }
  float m = v[0];
#pragma unroll
  for (int j = 1; j < 16; ++j) m = fmaxf(m, v[j]);
  m = wave_max64(m);
  __shared__ float sm[2];
  __shared__ float ss[2];
  const int wid = tid >> 6;
  if ((tid & 63) == 0) sm[wid] = m;
  __syncthreads();
  m = fmaxf(sm[0], sm[1]);
  float s = 0.f;
#pragma unroll
  for (int j = 0; j < 16; ++j) s += expf(v[j] - m);
  s = wave_sum64(s);
  if ((tid & 63) == 0) ss[wid] = s;
  __syncthreads();
  if (tid == 0) lse[row] = m + logf(ss[0] + ss[1]);
}

// ---------------- K2: transpose W (S,V) f32 -> Et (V,S) bf16 ----------------
__global__ void k_transpose(const float* __restrict__ W, unsigned short* __restrict__ Et) {
  __shared__ float t[64][33];           // [s][v], padded
  const int s0 = blockIdx.x * 64;
  const int v0 = blockIdx.y * 32;
  const int tid = threadIdx.x;          // 256
  const int r = tid >> 3, c = (tid & 7) * 4;
#pragma unroll
  for (int it = 0; it < 2; ++it) {
    const float* src = W + (size_t)(s0 + r + it * 32) * V_VOC + v0 + c;
    float4 q = *(const float4*)src;
    t[r + it * 32][c + 0] = q.x; t[r + it * 32][c + 1] = q.y;
    t[r + it * 32][c + 2] = q.z; t[r + it * 32][c + 3] = q.w;
  }
  __syncthreads();
  const int vv = tid >> 3, cs = (tid & 7) * 8;
  unsigned int w0 = (unsigned int)f2bf(t[cs + 0][vv]) | ((unsigned int)f2bf(t[cs + 1][vv]) << 16);
  unsigned int w1 = (unsigned int)f2bf(t[cs + 2][vv]) | ((unsigned int)f2bf(t[cs + 3][vv]) << 16);
  unsigned int w2 = (unsigned int)f2bf(t[cs + 4][vv]) | ((unsigned int)f2bf(t[cs + 5][vv]) << 16);
  unsigned int w3 = (unsigned int)f2bf(t[cs + 6][vv]) | ((unsigned int)f2bf(t[cs + 7][vv]) << 16);
  uint4 out = make_uint4(w0, w1, w2, w3);
  *(uint4*)(Et + (size_t)(v0 + vv) * S_TOT + s0 + cs) = out;
}

// ---------------- K3: transition softmax -> probabilities, (7,S) bf16 ----------------
__global__ void k_tsoftmax(const float* __restrict__ tw, unsigned short* __restrict__ Tt) {
  const int s = blockIdx.x * 256 + threadIdx.x;
  float x[7];
#pragma unroll
  for (int k = 0; k < 7; ++k) x[k] = tw[(size_t)s * 7 + k];
  float m = x[0];
#pragma unroll
  for (int k = 1; k < 7; ++k) m = fmaxf(m, x[k]);
  float e[7]; float sum = 0.f;
#pragma unroll
  for (int k = 0; k < 7; ++k) { e[k] = expf(x[k] - m); sum += e[k]; }
  const float inv = 1.f / sum;
#pragma unroll
  for (int k = 0; k < 7; ++k) Tt[(size_t)k * S_TOT + s] = f2bf(e[k] * inv);
}

// ---------------- K4: em[bt,s] = sum_l Et[tok_l][s] - L*lse[s] ----------------
__global__ void k_em(const unsigned short* __restrict__ Et, const int* __restrict__ stories,
                     const float* __restrict__ lse, float* __restrict__ em) {
  const int bt = blockIdx.y;
  __shared__ int toks[L_L];
  if (threadIdx.x < L_L) toks[threadIdx.x] = stories[bt * L_L + threadIdx.x];
  __syncthreads();
  const int s = blockIdx.x * 2048 + threadIdx.x * 8;
  float acc[8] = {0.f, 0.f, 0.f, 0.f, 0.f, 0.f, 0.f, 0.f};
#pragma unroll
  for (int l = 0; l < L_L; ++l) {
    const uint4* p = (const uint4*)(Et + ((size_t)toks[l] << 14) + s);
    uint4 q = *p;
    acc[0] += bflo(q.x); acc[1] += bfhi(q.x);
    acc[2] += bflo(q.y); acc[3] += bfhi(q.y);
    acc[4] += bflo(q.z); acc[5] += bfhi(q.z);
    acc[6] += bflo(q.w); acc[7] += bfhi(q.w);
  }
  const float4* lp = (const float4*)(lse + s);
  float4 l0 = lp[0], l1 = lp[1];
  float4 o0, o1;
  o0.x = acc[0] - 16.f * l0.x; o0.y = acc[1] - 16.f * l0.y;
  o0.z = acc[2] - 16.f * l0.z; o0.w = acc[3] - 16.f * l0.w;
  o1.x = acc[4] - 16.f * l1.x; o1.y = acc[5] - 16.f * l1.y;
  o1.z = acc[6] - 16.f * l1.z; o1.w = acc[7] - 16.f * l1.w;
  float4* op = (float4*)(em + (size_t)bt * S_TOT + s);
  op[0] = o0; op[1] = o1;
}

// ---------------- K5: scaled forward recursion, one block per batch ----------------
// thread owns 2x (pair) x 8z. x+-1 via DPP, z via regs, y via LDS float2.
// One barrier/step. Shift for step t = max(em_{t-1}) (lag-1 max: exact for any shift,
// only needs to bound the fp32 exp range). em loaded once/step, no prefetch buffers.
// amdgpu_waves_per_eu(4,4): LDS (132KB) caps us at 1 block/CU = 4 waves/SIMD anyway,
// so pin the backend to 4 waves/EU -> 128-VGPR budget -> no scratch spill of Tp/qrv.

__device__ __forceinline__ float block_sum16(float v, float* row, int tid, int wid) {
  v = wave_sum64(v);
  if ((tid & 63) == 0) row[wid] = v;
  __syncthreads();
  return row16_sum(row[tid & 15]);
}
__device__ __forceinline__ float block_max16(float v, float* row, int tid, int wid) {
  v = wave_max64(v);
  if ((tid & 63) == 0) row[wid] = v;
  __syncthreads();
  return row16_max(row[tid & 15]);
}

#define TLO(k,i) __uint_as_float(Tp[k][i] << 16)
#define THI(k,i) __uint_as_float(Tp[k][i] & 0xffff0000u)

__global__ void __launch_bounds__(1024)
__attribute__((amdgpu_waves_per_eu(4, 4)))
k_forward(const float* __restrict__ em, const float* __restrict__ prior_w,
          const unsigned short* __restrict__ Tt, float* __restrict__ out) {
  __shared__ __align__(16) float qbuf[2][16448];   // interior at [32, 16416)
  __shared__ __align__(16) float partS[2][16];
  __shared__ __align__(16) float partM[2][16];
  __shared__ __align__(16) float scr0[4][16];
  const int tid = threadIdx.x;
  const int b   = blockIdx.x;
  const int ux = tid & 15, uy = (tid >> 4) & 31, uz = tid >> 9;
  const int rowxy = uy * 32 + 2 * ux;
  const int soff  = uz * 8192 + rowxy;             // state index of (i=0, j=0)
  const int zoff  = uz ? (6144 + rowxy) : rowxy;   // z-2 plane base (uz=0 reads garbage, masked)
  const int wid = tid >> 6;

  if (tid < 64) {                                  // zero guards (y-edge reads, masked by T=0)
    int g = (tid < 32) ? tid : (16416 + tid - 32);
    qbuf[0][g] = 0.f; qbuf[1][g] = 0.f;
  }

  const float* emb = em + (size_t)b * T_T * S_TOT;

  // ---- t = 0 ----
  float2 pw[8], e0[8];
#pragma unroll
  for (int i = 0; i < 8; ++i) pw[i] = *(const float2*)(prior_w + soff + i * 1024);
#pragma unroll
  for (int i = 0; i < 8; ++i) e0[i] = *(const float2*)(emb + soff + i * 1024);

  float pm = fmaxf(pw[0].x, pw[0].y);
#pragma unroll
  for (int i = 1; i < 8; ++i) pm = fmaxf(pm, fmaxf(pw[i].x, pw[i].y));
  const float Mp = block_max16(pm, scr0[0], tid, wid);
  float pse = 0.f;
#pragma unroll
  for (int i = 0; i < 8; ++i) pse += __expf(pw[i].x - Mp) + __expf(pw[i].y - Mp);
  const float Sp = block_sum16(pse, scr0[1], tid, wid);
  const float prior_lse = Mp + __logf(Sp);

  float vm = e0[0].x + pw[0].x;
  float e0m = fmaxf(e0[0].x, e0[0].y);
#pragma unroll
  for (int i = 0; i < 8; ++i) {
    vm = fmaxf(vm, fmaxf(e0[i].x + pw[i].x, e0[i].y + pw[i].y));
    e0m = fmaxf(e0m, fmaxf(e0[i].x, e0[i].y));
  }
  const float M0 = block_max16(vm, scr0[2], tid, wid);

  float2 qrv[8]; float ps0 = 0.f;
#pragma unroll
  for (int i = 0; i < 8; ++i) {
    float u0 = __expf(e0[i].x + pw[i].x - M0);
    float u1 = __expf(e0[i].y + pw[i].y - M0);
    qrv[i] = make_float2(u0, u1);
    *(float2*)(&qbuf[0][32 + soff + i * 1024]) = qrv[i];
    ps0 += u0 + u1;
  }
  const float Z0 = block_sum16(ps0, scr0[3], tid, wid);
  const float lgZ = __logf(Z0);
  float C = M0 - prior_lse + lgZ;
  // lag-1 shift for t=1: max of em_0 (any shift is exact; only bounds exp range)
  const float M1reg = block_max16(e0m, scr0[0], tid, wid);

  // ---- transition table into registers (after t0 so pw/e0 regs are dead) ----
  unsigned Tp[7][8];
  const int offs[7] = {0, 1, -1, 32, -32, 1024, 2048};
#pragma unroll
  for (int k = 0; k < 7; ++k) {
#pragma unroll
    for (int i = 0; i < 8; ++i) {
      unsigned w = 0;
#pragma unroll
      for (int j = 0; j < 2; ++j) {
        const int x = 2 * ux + j, z = uz * 8 + i;
        const int si = soff + i * 1024 + j;
        int prev = si - offs[k];
        prev = prev < 0 ? 0 : (prev > S_TOT - 1 ? S_TOT - 1 : prev);
        const bool valid = (k == 0)
          || (k == 1 && x > 0)  || (k == 2 && x < 31)
          || (k == 3 && uy > 0) || (k == 4 && uy < 31)
          || (k == 5 && z >= 1) || (k == 6 && z >= 2);
        unsigned tv = valid ? (unsigned)Tt[(size_t)k * S_TOT + prev] : 0u;
        w |= tv << (16 * j);
      }
      Tp[k][i] = w;
    }
  }

#define STEP(TT, FIRST) { \
    const int tt = (TT); \
    float2 emr[8]; \
    { const float* et = emb + (size_t)tt * S_TOT + soff; \
      _Pragma("unroll") for (int i = 0; i < 8; ++i) emr[i] = *(const float2*)(et + i * 1024); } \
    float Mt, lzp; \
    if (FIRST) { Mt = M1reg; lzp = lgZ; } \
    else { \
      lzp = __logf(row16_sum(partS[(tt - 1) & 1][ux])); \
      Mt  = row16_max(partM[tt & 1][ux]); \
      C += lzp; \
    } \
    C += Mt; \
    const float shift = Mt + lzp; \
    const float* qc = &qbuf[(tt - 1) & 1][32]; \
    float* qw = &qbuf[tt & 1][32]; \
    float2 q2v = *(const float2*)(qc + zoff); \
    float2 q1v = *(const float2*)(qc + zoff + 1024); \
    float ps = 0.f; \
    float nm = fmaxf(emr[0].x, emr[0].y); \
    _Pragma("unroll") for (int i = 0; i < 8; ++i) { \
      const int si = soff + i * 1024; \
      float2 ym = *(const float2*)(qc + si - 32); \
      float2 yp = *(const float2*)(qc + si + 32); \
      const float2 qo = qrv[i]; \
      const float xl = dpp_rshr1(qo.y); \
      const float xr = dpp_rshl1(qo.x); \
      float sig0 = qo.x*TLO(0,i) + xl*TLO(1,i) + qo.y*TLO(2,i) + ym.x*TLO(3,i) \
                 + yp.x*TLO(4,i) + q1v.x*TLO(5,i) + q2v.x*TLO(6,i); \
      float sig1 = qo.y*THI(0,i) + qo.x*THI(1,i) + xr*THI(2,i) + ym.y*THI(3,i) \
                 + yp.y*THI(4,i) + q1v.y*THI(5,i) + q2v.y*THI(6,i); \
      nm = fmaxf(nm, fmaxf(emr[i].x, emr[i].y)); \
      const float u0 = __expf(emr[i].x - shift) * sig0; \
      const float u1 = __expf(emr[i].y - shift) * sig1; \
      ps += u0 + u1; \
      const float2 uu = make_float2(u0, u1); \
      qrv[i] = uu; \
      *(float2*)(qw + si) = uu; \
      q2v = q1v; q1v = qo; \
    } \
    ps = wave_sum64(ps); \
    nm = wave_max64(nm); \
    if ((tid & 63) == 0) { partS[tt & 1][wid] = ps; partM[(tt + 1) & 1][wid] = nm; } \
    __syncthreads(); \
  }

  STEP(1, 1)
  for (int t = 2; t < T_T; t += 2) {
    STEP(t, 0)
    STEP(t + 1, 0)
  }
  C += __logf(row16_sum(partS[1][ux]));   // Z for t=63 (63&1 == 1)
  if (tid == 0) out[b] = C;
#undef STEP
}

extern "C" void kernel_launch(void* const* d_in, const int* in_sizes, int n_in,
                              void* d_out, int out_size, void* d_ws, size_t ws_size,
                              hipStream_t stream) {
  (void)in_sizes; (void)n_in; (void)out_size; (void)ws_size;
  const int*   stories      = (const int*)d_in[0];
  const float* emission_w   = (const float*)d_in[3];
  const float* transition_w = (const float*)d_in[4];
  const float* prior_w      = (const float*)d_in[5];
  float* out = (float*)d_out;
  char* ws = (char*)d_ws;
  unsigned short* Et = (unsigned short*)(ws + OFF_ET);
  float*          em = (float*)(ws + OFF_EM);
  float*         lse = (float*)(ws + OFF_LSE);
  unsigned short* Tt = (unsigned short*)(ws + OFF_TT);

  hipLaunchKernelGGL(k_row_lse,   dim3(S_TOT),   dim3(128), 0, stream, emission_w, lse);
  hipLaunchKernelGGL(k_transpose, dim3(256, 64), dim3(256), 0, stream, emission_w, Et);
  hipLaunchKernelGGL(k_tsoftmax,  dim3(64),      dim3(256), 0, stream, transition_w, Tt);
  hipLaunchKernelGGL(k_em,        dim3(8, 2048), dim3(256), 0, stream, Et, stories, lse, em);
  hipLaunchKernelGGL(k_forward,   dim3(B_B),     dim3(1024), 0, stream, em, prior_w, Tt, out);
}

// Round 8
// 685.937 us; speedup vs baseline: 1.8854x; 1.7706x over previous
//
#include <hip/hip_runtime.h>
#include <hip/hip_bf16.h>
#include <cstdint>
#include <math.h>

#define S_TOT 16384
#define V_VOC 2048
#define B_B   32
#define T_T   64
#define L_L   16

// ws layout (bytes): ET 64MB | EM 134MB | LSE 64KB | MEMAX 8KB.
// T03/T46 OVERLAY the Et region (Et dead after k_em; k_tin runs after k_em).
// Total footprint <= round-1 proven layout.
static const size_t OFF_ET  = 0;
static const size_t OFF_EM  = 67108864;
static const size_t OFF_LSE = OFF_EM + 134217728;
static const size_t OFF_MX  = OFF_LSE + 65536;
static const size_t OFF_T03 = 0;         // overlay Et
static const size_t OFF_T46 = 131072;    // overlay Et + 128KB

__device__ __forceinline__ unsigned short f2bf(float f) {
  unsigned int u = __float_as_uint(f);
  u = (u + 0x7fffu + ((u >> 16) & 1u)) >> 16;   // round-to-nearest-even
  return (unsigned short)u;
}
__device__ __forceinline__ float bflo(unsigned int w) { return __uint_as_float(w << 16); }
__device__ __forceinline__ float bfhi(unsigned int w) { return __uint_as_float(w & 0xffff0000u); }

// order-preserving float<->uint for atomicMax on negatives
__device__ __forceinline__ unsigned f2ord(float x) {
  unsigned b = __float_as_uint(x);
  return b ^ (unsigned)(((int)b >> 31) | 0x80000000);
}
__device__ __forceinline__ float ord2f(unsigned u) {
  unsigned b = (u & 0x80000000u) ? (u ^ 0x80000000u) : ~u;
  return __uint_as_float(b);
}

// ---- DPP helpers (ctrl must be ICE -> template param) ----
template <int CTRL>
__device__ __forceinline__ float dppf(float v) {
  return __int_as_float(__builtin_amdgcn_update_dpp(0, __float_as_int(v), CTRL, 0xf, 0xf, true));
}
__device__ __forceinline__ float dpp_rshr1(float v) { return dppf<0x111>(v); } // lane n <- n-1 (16-row)
__device__ __forceinline__ float dpp_rshl1(float v) { return dppf<0x101>(v); } // lane n <- n+1
__device__ __forceinline__ float row16_sum(float v) {
  v += dppf<0xB1>(v); v += dppf<0x4E>(v); v += dppf<0x141>(v); v += dppf<0x140>(v);
  return v;
}
__device__ __forceinline__ float row16_max(float v) {
  v = fmaxf(v, dppf<0xB1>(v)); v = fmaxf(v, dppf<0x4E>(v));
  v = fmaxf(v, dppf<0x141>(v)); v = fmaxf(v, dppf<0x140>(v));
  return v;
}
__device__ __forceinline__ float wave_sum64(float v) {
  v = row16_sum(v); v += __shfl_xor(v, 16); v += __shfl_xor(v, 32); return v;
}
__device__ __forceinline__ float wave_max64(float v) {
  v = row16_max(v); v = fmaxf(v, __shfl_xor(v, 16)); v = fmaxf(v, __shfl_xor(v, 32)); return v;
}

// ---------------- K1: per-state logsumexp over vocab (+ Memax init) ----------------
__global__ void k_row_lse(const float* __restrict__ W, float* __restrict__ lse,
                          unsigned* __restrict__ Memax) {
  const int row = blockIdx.x;
  const int tid = threadIdx.x;          // 128 threads
  if (tid == 0 && row < B_B * T_T) Memax[row] = 0u;   // 0 decodes below any real value
  const float4* rp = (const float4*)(W + (size_t)row * V_VOC);
  float v[16];
#pragma unroll
  for (int j = 0; j < 4; ++j) {
    float4 q = rp[tid + j * 128];
    v[4*j+0] = q.x; v[4*j+1] = q.y; v[4*j+2] = q.z; v[4*j+3] = q.w;
  }
  float m = v[0];
#pragma unroll
  for (int j = 1; j < 16; ++j) m = fmaxf(m, v[j]);
  m = wave_max64(m);
  __shared__ float sm[2];
  __shared__ float ss[2];
  const int wid = tid >> 6;
  if ((tid & 63) == 0) sm[wid] = m;
  __syncthreads();
  m = fmaxf(sm[0], sm[1]);
  float s = 0.f;
#pragma unroll
  for (int j = 0; j < 16; ++j) s += expf(v[j] - m);
  s = wave_sum64(s);
  if ((tid & 63) == 0) ss[wid] = s;
  __syncthreads();
  if (tid == 0) lse[row] = m + logf(ss[0] + ss[1]);
}

// ---------------- K2: transpose W (S,V) f32 -> Et (V,S) bf16 ----------------
__global__ void k_transpose(const float* __restrict__ W, unsigned short* __restrict__ Et) {
  __shared__ float t[64][33];
  const int s0 = blockIdx.x * 64;
  const int v0 = blockIdx.y * 32;
  const int tid = threadIdx.x;          // 256
  const int r = tid >> 3, c = (tid & 7) * 4;
#pragma unroll
  for (int it = 0; it < 2; ++it) {
    const float* src = W + (size_t)(s0 + r + it * 32) * V_VOC + v0 + c;
    float4 q = *(const float4*)src;
    t[r + it * 32][c + 0] = q.x; t[r + it * 32][c + 1] = q.y;
    t[r + it * 32][c + 2] = q.z; t[r + it * 32][c + 3] = q.w;
  }
  __syncthreads();
  const int vv = tid >> 3, cs = (tid & 7) * 8;
  unsigned int w0 = (unsigned int)f2bf(t[cs + 0][vv]) | ((unsigned int)f2bf(t[cs + 1][vv]) << 16);
  unsigned int w1 = (unsigned int)f2bf(t[cs + 2][vv]) | ((unsigned int)f2bf(t[cs + 3][vv]) << 16);
  unsigned int w2 = (unsigned int)f2bf(t[cs + 4][vv]) | ((unsigned int)f2bf(t[cs + 5][vv]) << 16);
  unsigned int w3 = (unsigned int)f2bf(t[cs + 6][vv]) | ((unsigned int)f2bf(t[cs + 7][vv]) << 16);
  uint4 out = make_uint4(w0, w1, w2, w3);
  *(uint4*)(Et + (size_t)(v0 + vv) * S_TOT + s0 + cs) = out;
}

// ---------------- K3: em[bt,s] = sum_l Et[tok_l][s] - L*lse[s]  (+ per-bt max) ----------------
__global__ void k_em(const unsigned short* __restrict__ Et, const int* __restrict__ stories,
                     const float* __restrict__ lse, float* __restrict__ em,
                     unsigned* __restrict__ Memax) {
  const int bt = blockIdx.y;
  __shared__ int toks[L_L];
  if (threadIdx.x < L_L) toks[threadIdx.x] = stories[bt * L_L + threadIdx.x];
  __syncthreads();
  const int s = blockIdx.x * 2048 + threadIdx.x * 8;
  float acc[8] = {0.f, 0.f, 0.f, 0.f, 0.f, 0.f, 0.f, 0.f};
#pragma unroll
  for (int l = 0; l < L_L; ++l) {
    const uint4* p = (const uint4*)(Et + ((size_t)toks[l] << 14) + s);
    uint4 q = *p;
    acc[0] += bflo(q.x); acc[1] += bfhi(q.x);
    acc[2] += bflo(q.y); acc[3] += bfhi(q.y);
    acc[4] += bflo(q.z); acc[5] += bfhi(q.z);
    acc[6] += bflo(q.w); acc[7] += bfhi(q.w);
  }
  const float4* lp = (const float4*)(lse + s);
  float4 l0 = lp[0], l1 = lp[1];
  float4 o0, o1;
  o0.x = acc[0] - 16.f * l0.x; o0.y = acc[1] - 16.f * l0.y;
  o0.z = acc[2] - 16.f * l0.z; o0.w = acc[3] - 16.f * l0.w;
  o1.x = acc[4] - 16.f * l1.x; o1.y = acc[5] - 16.f * l1.y;
  o1.z = acc[6] - 16.f * l1.z; o1.w = acc[7] - 16.f * l1.w;
  float4* op = (float4*)(em + (size_t)bt * S_TOT + s);
  op[0] = o0; op[1] = o1;
  float mm = fmaxf(fmaxf(fmaxf(o0.x, o0.y), fmaxf(o0.z, o0.w)),
                   fmaxf(fmaxf(o1.x, o1.y), fmaxf(o1.z, o1.w)));
  mm = wave_max64(mm);
  if ((threadIdx.x & 63) == 0) atomicMax(Memax + bt, f2ord(mm));
}

// ---------------- K4: incoming-transition table, edge masks baked in ----------------
// Tin[s][k] = softmax(tw[s-off_k])[k] if move valid else 0; packed bf16 (lo=even x, hi=odd x).
// T03[p] = {k0,k1,k2,k3}, T46[p] = {k4,k5,k6,0} for state pair p = s/2.
__global__ void k_tin(const float* __restrict__ tw, uint4* __restrict__ T03,
                      uint4* __restrict__ T46) {
  const int p = blockIdx.x * 256 + threadIdx.x;   // 8192 pairs
  const int s0 = p * 2;
  const int x0 = s0 & 31, y = (s0 >> 5) & 31, z = s0 >> 10;
  const int offs[7] = {0, 1, -1, 32, -32, 1024, 2048};
  unsigned pk[7];
#pragma unroll
  for (int k = 0; k < 7; ++k) {
    unsigned lo = 0, hi = 0;
    const bool v0 = (k == 0) || (k == 1 && x0 > 0)  || (k == 2 && x0 < 31)
                 || (k == 3 && y > 0) || (k == 4 && y < 31)
                 || (k == 5 && z >= 1) || (k == 6 && z >= 2);
    const bool v1 = (k == 0) || (k == 1)            || (k == 2 && x0 < 30)
                 || (k == 3 && y > 0) || (k == 4 && y < 31)
                 || (k == 5 && z >= 1) || (k == 6 && z >= 2);
    if (v0) {
      const float* w = tw + (size_t)(s0 - offs[k]) * 7;
      float xv[7]; float m = -3.0e38f;
#pragma unroll
      for (int j = 0; j < 7; ++j) { xv[j] = w[j]; m = fmaxf(m, xv[j]); }
      float sum = 0.f; float ek = 0.f;
#pragma unroll
      for (int j = 0; j < 7; ++j) { float e = __expf(xv[j] - m); sum += e; if (j == k) ek = e; }
      lo = f2bf(ek / sum);
    }
    if (v1) {
      const float* w = tw + (size_t)(s0 + 1 - offs[k]) * 7;
      float xv[7]; float m = -3.0e38f;
#pragma unroll
      for (int j = 0; j < 7; ++j) { xv[j] = w[j]; m = fmaxf(m, xv[j]); }
      float sum = 0.f; float ek = 0.f;
#pragma unroll
      for (int j = 0; j < 7; ++j) { float e = __expf(xv[j] - m); sum += e; if (j == k) ek = e; }
      hi = f2bf(ek / sum);
    }
    pk[k] = lo | (hi << 16);
  }
  T03[p] = make_uint4(pk[0], pk[1], pk[2], pk[3]);
  T46[p] = make_uint4(pk[4], pk[5], pk[6], 0u);
}

// ---------------- K5: scaled forward recursion, one block per batch ----------------
// No persistent per-thread tables: Tin streamed from L2 per step (2-iter lookahead),
// shift = Memax[b,t] + logZ_{t-1} (Memax precomputed by k_em). One barrier per step.
// Steady-state live regs ~55-60 -> fits the 64-VGPR budget, no scratch spill.
__device__ __forceinline__ float block_sum16(float v, float* row, int tid, int wid) {
  v = wave_sum64(v);
  if ((tid & 63) == 0) row[wid] = v;
  __syncthreads();
  return row16_sum(row[tid & 15]);
}
__device__ __forceinline__ float block_max16(float v, float* row, int tid, int wid) {
  v = wave_max64(v);
  if ((tid & 63) == 0) row[wid] = v;
  __syncthreads();
  return row16_max(row[tid & 15]);
}

__global__ void __launch_bounds__(1024)
k_forward(const float* __restrict__ em, const float* __restrict__ prior_w,
          const uint4* __restrict__ T03, const uint4* __restrict__ T46,
          const unsigned* __restrict__ Memax, float* __restrict__ out) {
  __shared__ __align__(16) float qbuf[2][16448];   // interior at [32, 16416)
  __shared__ __align__(16) float partS[2][16];
  __shared__ __align__(16) float scr0[4][16];
  const int tid = threadIdx.x;
  const int b   = blockIdx.x;
  const int ux = tid & 15, uy = (tid >> 4) & 31, uz = tid >> 9;
  const int rowxy = uy * 32 + 2 * ux;
  const int soff  = uz * 8192 + rowxy;
  const int p0    = soff >> 1;
  const int zoff  = uz ? (6144 + rowxy) : rowxy;   // z-2 plane base (uz=0 garbage, masked)
  const int wid = tid >> 6;

  if (tid < 64) {                                  // zero guards
    int g = (tid < 32) ? tid : (16416 + tid - 32);
    qbuf[0][g] = 0.f; qbuf[1][g] = 0.f;
  }

  const float* emb = em + (size_t)b * T_T * S_TOT;

  // ---- t = 0 ----
  float2 pw[8], e0[8];
#pragma unroll
  for (int i = 0; i < 8; ++i) pw[i] = *(const float2*)(prior_w + soff + i * 1024);
#pragma unroll
  for (int i = 0; i < 8; ++i) e0[i] = *(const float2*)(emb + soff + i * 1024);

  float pm = fmaxf(pw[0].x, pw[0].y);
#pragma unroll
  for (int i = 1; i < 8; ++i) pm = fmaxf(pm, fmaxf(pw[i].x, pw[i].y));
  const float Mp = block_max16(pm, scr0[0], tid, wid);
  float pse = 0.f;
#pragma unroll
  for (int i = 0; i < 8; ++i) pse += __expf(pw[i].x - Mp) + __expf(pw[i].y - Mp);
  const float Sp = block_sum16(pse, scr0[1], tid, wid);
  const float prior_lse = Mp + __logf(Sp);

  float vm = e0[0].x + pw[0].x;
#pragma unroll
  for (int i = 0; i < 8; ++i) vm = fmaxf(vm, fmaxf(e0[i].x + pw[i].x, e0[i].y + pw[i].y));
  const float M0 = block_max16(vm, scr0[2], tid, wid);

  float ps0 = 0.f;
#pragma unroll
  for (int i = 0; i < 8; ++i) {
    float u0 = __expf(e0[i].x + pw[i].x - M0);
    float u1 = __expf(e0[i].y + pw[i].y - M0);
    *(float2*)(&qbuf[0][32 + soff + i * 1024]) = make_float2(u0, u1);
    ps0 += u0 + u1;
  }
  const float Z0 = block_sum16(ps0, scr0[3], tid, wid);   // barrier publishes qbuf[0] too
  const float lgZ = __logf(Z0);
  float C = M0 - prior_lse + lgZ;

  const unsigned* mxp = Memax + b * T_T;
  unsigned long long a03 = (unsigned long long)T03;
  unsigned long long a46 = (unsigned long long)T46;

  for (int t = 1; t < T_T; ++t) {
    // launder Tin bases so LICM can't hoist the (step-invariant) table loads into 64 regs
    asm volatile("" : "+s"(a03), "+s"(a46));
    const uint4* t03 = (const uint4*)a03;
    const uint4* t46 = (const uint4*)a46;

    float2 emr[8];
    const float* et = emb + (size_t)t * S_TOT + soff;
#pragma unroll
    for (int i = 0; i < 8; ++i) emr[i] = *(const float2*)(et + i * 1024);

    uint4 ta[8], tb[8];
    ta[0] = t03[p0];       tb[0] = t46[p0];
    ta[1] = t03[p0 + 512]; tb[1] = t46[p0 + 512];

    const float Mt = ord2f(mxp[t]);
    float lzp;
    if (t == 1) lzp = lgZ;
    else { lzp = __logf(row16_sum(partS[(t - 1) & 1][ux])); C += lzp; }
    C += Mt;
    const float shift = Mt + lzp;

    const float* qc = &qbuf[(t - 1) & 1][32];
    float* qw = &qbuf[t & 1][32];
    float2 q2v = *(const float2*)(qc + zoff);          // garbage at uz=0 (masked by Tin=0)
    float2 q1v = *(const float2*)(qc + zoff + 1024);
    float ps = 0.f;
#pragma unroll
    for (int i = 0; i < 8; ++i) {
      if (i + 2 < 8) { ta[i + 2] = t03[p0 + (i + 2) * 512]; tb[i + 2] = t46[p0 + (i + 2) * 512]; }
      const int si = soff + i * 1024;
      const float2 qo = *(const float2*)(qc + si);
      const float2 ym = *(const float2*)(qc + si - 32);
      const float2 yp = *(const float2*)(qc + si + 32);
      const float xl = dpp_rshr1(qo.y);
      const float xr = dpp_rshl1(qo.x);
      const uint4 A = ta[i], Bv = tb[i];
      float sig0 = qo.x * bflo(A.x) + xl   * bflo(A.y) + qo.y * bflo(A.z) + ym.x * bflo(A.w)
                 + yp.x * bflo(Bv.x) + q1v.x * bflo(Bv.y) + q2v.x * bflo(Bv.z);
      float sig1 = qo.y * bfhi(A.x) + qo.x * bfhi(A.y) + xr   * bfhi(A.z) + ym.y * bfhi(A.w)
                 + yp.y * bfhi(Bv.x) + q1v.y * bfhi(Bv.y) + q2v.y * bfhi(Bv.z);
      const float u0 = __expf(emr[i].x - shift) * sig0;
      const float u1 = __expf(emr[i].y - shift) * sig1;
      ps += u0 + u1;
      *(float2*)(qw + si) = make_float2(u0, u1);
      q2v = q1v; q1v = qo;
    }
    ps = wave_sum64(ps);
    if ((tid & 63) == 0) partS[t & 1][wid] = ps;
    __syncthreads();
  }
  C += __logf(row16_sum(partS[(T_T - 1) & 1][ux]));   // logZ of t=63
  if (tid == 0) out[b] = C;
}

extern "C" void kernel_launch(void* const* d_in, const int* in_sizes, int n_in,
                              void* d_out, int out_size, void* d_ws, size_t ws_size,
                              hipStream_t stream) {
  (void)in_sizes; (void)n_in; (void)out_size; (void)ws_size;
  const int*   stories      = (const int*)d_in[0];
  const float* emission_w   = (const float*)d_in[3];
  const float* transition_w = (const float*)d_in[4];
  const float* prior_w      = (const float*)d_in[5];
  float* out = (float*)d_out;
  char* ws = (char*)d_ws;
  unsigned short* Et = (unsigned short*)(ws + OFF_ET);
  float*          em = (float*)(ws + OFF_EM);
  float*         lse = (float*)(ws + OFF_LSE);
  unsigned*       mx = (unsigned*)(ws + OFF_MX);
  uint4*         t03 = (uint4*)(ws + OFF_T03);
  uint4*         t46 = (uint4*)(ws + OFF_T46);

  hipLaunchKernelGGL(k_row_lse,   dim3(S_TOT),   dim3(128), 0, stream, emission_w, lse, mx);
  hipLaunchKernelGGL(k_transpose, dim3(256, 64), dim3(256), 0, stream, emission_w, Et);
  hipLaunchKernelGGL(k_em,        dim3(8, 2048), dim3(256), 0, stream, Et, stories, lse, em, mx);
  hipLaunchKernelGGL(k_tin,       dim3(32),      dim3(256), 0, stream, transition_w, t03, t46);
  hipLaunchKernelGGL(k_forward,   dim3(B_B),     dim3(1024), 0, stream, em, prior_w, t03, t46, mx, out);
}